// Round 1
// baseline (323.639 us; speedup 1.0000x reference)
//
#include <hip/hip_runtime.h>
#include <math.h>

// Problem dims
#define UNITS 512
#define MEMN  16384
#define BATCH 64

// d_out offsets (floats): h, c, read, m, c_wu, c_wlu, c_wr
#define OUT_H    0
#define OUT_C    32768
#define OUT_READ 65536
#define OUT_M    98304
#define OUT_CWU  8486912
#define OUT_CWLU 9535488
#define OUT_CWR  10584064

// ws offsets (floats)
#define WS_PRE   0         // 64*4608 preactivations
#define WS_NKEY  294912    // 512*64 normalized key^T (K-major)
#define WS_PMIN  327680    // 256*64 partial min values
#define WS_PIDX  344064    // 256*64 partial min indices (int)
#define WS_MINF  360448    // 64 final min
#define WS_IDXF  360512    // 64 final argmin (int)

__device__ __forceinline__ float hsig(float x) {
    return fminf(fmaxf(0.2f * x + 0.5f, 0.f), 1.f);
}

// ---------------------------------------------------------------------------
// K1: preactivations. Virtual column space 4608 = [x:2048 | hk:2048 | r_i:512]
// C(64 x 4608) tiles of 32 cols, K=512, f32 LDS-tiled GEMM.
// ---------------------------------------------------------------------------
__global__ __launch_bounds__(256) void k_preact(
    const float* __restrict__ inputs, const float* __restrict__ h_tm1,
    const float* __restrict__ r_tm1, const float* __restrict__ wk,
    const float* __restrict__ rk, float* __restrict__ pre)
{
    __shared__ float As[64][33];
    __shared__ float Bs[32][33];
    const int vcol0 = blockIdx.x * 32;
    const float* A; const float* W; int wstride, wcol0;
    if (vcol0 < 2048)      { A = inputs; W = wk; wstride = 2048; wcol0 = vcol0; }
    else if (vcol0 < 4096) { A = h_tm1;  W = rk; wstride = 2560; wcol0 = vcol0 - 2048; }
    else                   { A = r_tm1;  W = rk; wstride = 2560; wcol0 = 2048 + (vcol0 - 4096); }
    const int tid = threadIdx.x;
    const int tx = tid & 15, ty = tid >> 4;
    float acc[4][2] = {};
    for (int k0 = 0; k0 < 512; k0 += 32) {
        for (int e = tid; e < 2048; e += 256) {
            int r = e >> 5, k = e & 31;
            As[r][k] = A[r * 512 + k0 + k];
        }
        for (int e = tid; e < 1024; e += 256) {
            int kk = e >> 5, c = e & 31;
            Bs[kk][c] = W[(k0 + kk) * wstride + wcol0 + c];
        }
        __syncthreads();
        #pragma unroll
        for (int kk = 0; kk < 32; ++kk) {
            float a0 = As[ty*4+0][kk], a1 = As[ty*4+1][kk];
            float a2 = As[ty*4+2][kk], a3 = As[ty*4+3][kk];
            float b0 = Bs[kk][tx*2+0], b1 = Bs[kk][tx*2+1];
            acc[0][0] += a0*b0; acc[0][1] += a0*b1;
            acc[1][0] += a1*b0; acc[1][1] += a1*b1;
            acc[2][0] += a2*b0; acc[2][1] += a2*b1;
            acc[3][0] += a3*b0; acc[3][1] += a3*b1;
        }
        __syncthreads();
    }
    #pragma unroll
    for (int i = 0; i < 4; ++i)
        #pragma unroll
        for (int j = 0; j < 2; ++j)
            pre[(ty*4+i) * 4608 + vcol0 + tx*2 + j] = acc[i][j];
}

// ---------------------------------------------------------------------------
// K1c: gate fusion -> h, c
// ---------------------------------------------------------------------------
__global__ __launch_bounds__(256) void k_gates(
    const float* __restrict__ pre, const float* __restrict__ bias,
    const float* __restrict__ c_tm1, float* __restrict__ out)
{
    int idx = blockIdx.x * 256 + threadIdx.x;   // 32768
    int b = idx >> 9, u = idx & 511;
    const float* p = pre + b * 4608;
    float xi = p[u]        + bias[u];
    float xf = p[512 + u]  + bias[512 + u];
    float xc = p[1024 + u] + bias[1024 + u];
    float xo = p[1536 + u] + bias[1536 + u];
    float hi = p[2048 + u], hf = p[2560 + u], hc = p[3072 + u], ho = p[3584 + u];
    float ri = p[4096 + u];
    float ig = hsig(xi + hi + ri);
    float fg = hsig(xf + hf);
    float cc = fg * c_tm1[idx] + ig * tanhf(xc + hc);
    float og = hsig(xo + ho);
    float hh = og * tanhf(cc);
    out[OUT_H + idx] = hh;
    out[OUT_C + idx] = cc;
}

// ---------------------------------------------------------------------------
// K1b: n_key^T (K-major, 512 x 64): per-batch L2 normalization of h
// ---------------------------------------------------------------------------
__global__ __launch_bounds__(256) void k_nkey(
    const float* __restrict__ h, float* __restrict__ nkeyT)
{
    int b = blockIdx.x, t = threadIdx.x;
    float v0 = h[b * 512 + t];
    float v1 = h[b * 512 + 256 + t];
    float ss = v0 * v0 + v1 * v1;
    __shared__ float red[4];
    for (int m = 1; m < 64; m <<= 1) ss += __shfl_xor(ss, m);
    if ((t & 63) == 0) red[t >> 6] = ss;
    __syncthreads();
    float tot = red[0] + red[1] + red[2] + red[3];
    float rn = rsqrtf(fmaxf(tot, 1e-12f));
    nkeyT[t * 64 + b]         = v0 * rn;
    nkeyT[(256 + t) * 64 + b] = v1 * rn;
}

// ---------------------------------------------------------------------------
// K2: cos GEMM (64 rows/block) + fused softmax (over B, row-local) + c_ww/c_wu
//     + per-block column min/argmin partials.
// ---------------------------------------------------------------------------
__global__ __launch_bounds__(256) void k_cos(
    const float* __restrict__ m_tm1, const float* __restrict__ nkeyT,
    const float* __restrict__ cwr_tm1, const float* __restrict__ cwlu_tm1,
    const float* __restrict__ cwu_tm1, const float* __restrict__ wgp,
    float* out, float* __restrict__ pmin, int* __restrict__ pidx)
{
    __shared__ float As[64][33];
    __shared__ float Bs[32][64];
    __shared__ float Cs[64][65];
    const int blk = blockIdx.x, row0 = blk * 64;
    const int tid = threadIdx.x;
    const int tx = tid & 15, ty = tid >> 4;
    const float* A = m_tm1 + (size_t)row0 * 512;
    float acc[4][4] = {};
    float ss[4] = {};
    for (int k0 = 0; k0 < 512; k0 += 32) {
        for (int e = tid; e < 2048; e += 256) {
            int r = e >> 5, k = e & 31;
            As[r][k] = A[r * 512 + k0 + k];
        }
        for (int e = tid; e < 2048; e += 256) {
            int kk = e >> 6, b = e & 63;
            Bs[kk][b] = nkeyT[(k0 + kk) * 64 + b];
        }
        __syncthreads();
        #pragma unroll
        for (int kk = 0; kk < 32; ++kk) {
            float a[4], bb[4];
            #pragma unroll
            for (int i = 0; i < 4; ++i) a[i] = As[ty*4+i][kk];
            #pragma unroll
            for (int j = 0; j < 4; ++j) bb[j] = Bs[kk][tx*4+j];
            #pragma unroll
            for (int i = 0; i < 4; ++i) {
                ss[i] += a[i] * a[i];   // row sumsq (redundant across tx, consistent)
                #pragma unroll
                for (int j = 0; j < 4; ++j) acc[i][j] += a[i] * bb[j];
            }
        }
        __syncthreads();
    }
    // cos = (m . n_key) * rsqrt(sumsq(m_row))
    #pragma unroll
    for (int i = 0; i < 4; ++i) {
        float rn = rsqrtf(fmaxf(ss[i], 1e-12f));
        #pragma unroll
        for (int j = 0; j < 4; ++j) Cs[ty*4+i][tx*4+j] = acc[i][j] * rn;
    }
    __syncthreads();

    const float wg = 1.f / (1.f + expf(-wgp[0]));
    // softmax over the 64 batch columns of each row (4 lanes per row)
    int row = tid >> 2, sub = tid & 3;
    float mx = -INFINITY;
    for (int j = sub; j < 64; j += 4) mx = fmaxf(mx, Cs[row][j]);
    mx = fmaxf(mx, __shfl_xor(mx, 1));
    mx = fmaxf(mx, __shfl_xor(mx, 2));
    float sm = 0.f;
    for (int j = sub; j < 64; j += 4) {
        float e = expf(Cs[row][j] - mx);
        Cs[row][j] = e;
        sm += e;
    }
    sm += __shfl_xor(sm, 1);
    sm += __shfl_xor(sm, 2);
    float inv = 1.f / sm;
    int grow = row0 + row;
    for (int j = sub; j < 64; j += 4) {
        float p = Cs[row][j] * inv;
        int g = grow * 64 + j;
        out[OUT_CWR + g] = p;
        float cww = wg * cwr_tm1[g] + (1.f - wg) + cwlu_tm1[g];
        float cwu = 0.95f * cwu_tm1[g] + p + cww;
        out[OUT_CWU + g] = cwu;
        Cs[row][j] = cwu;   // reuse for min phase
    }
    __syncthreads();
    // per-column min/argmin partial over this block's 64 rows
    int col = tid >> 2;
    float bv = INFINITY; int bi = 0;
    for (int r = sub; r < 64; r += 4) {
        float v = Cs[r][col];
        if (v < bv) { bv = v; bi = r; }
    }
    #pragma unroll
    for (int mk = 1; mk < 4; mk <<= 1) {
        float ov = __shfl_xor(bv, mk);
        int   oi = __shfl_xor(bi, mk);
        if (ov < bv || (ov == bv && oi < bi)) { bv = ov; bi = oi; }
    }
    if (sub == 0) { pmin[blk * 64 + col] = bv; pidx[blk * 64 + col] = row0 + bi; }
}

// ---------------------------------------------------------------------------
// K3: final min/argmin reduce (first-occurrence semantics like jnp.argmin)
// ---------------------------------------------------------------------------
__global__ void k_minfinal(const float* __restrict__ pmin, const int* __restrict__ pidx,
                           float* __restrict__ minf, int* __restrict__ idxf)
{
    int col = threadIdx.x;   // 64
    float bv = INFINITY; int bi = 0x7fffffff;
    for (int p = 0; p < 256; ++p) {
        float v = pmin[p * 64 + col];
        int   i = pidx[p * 64 + col];
        if (v < bv || (v == bv && i < bi)) { bv = v; bi = i; }
    }
    minf[col] = bv; idxf[col] = bi;
}

// ---------------------------------------------------------------------------
// K4: c_wlu compare + keep mask + m = m_tm1*keep + c_ww @ h (K=64)
// ---------------------------------------------------------------------------
__global__ __launch_bounds__(256) void k_update(
    const float* __restrict__ m_tm1, const float* __restrict__ cwr_tm1,
    const float* __restrict__ cwlu_tm1, const float* __restrict__ wgp,
    const float* __restrict__ minf, const int* __restrict__ idxf,
    float* out)
{
    __shared__ float Hs[64][512];   // 128 KiB: full h
    __shared__ float Ws[64][65];    // c_ww tile
    __shared__ float keepf[64];
    __shared__ float minS[64];
    __shared__ int   idxS[64];
    const int blk = blockIdx.x, tid = threadIdx.x, row0 = blk * 64;
    const float wg = 1.f / (1.f + expf(-wgp[0]));
    if (tid < 64) { minS[tid] = minf[tid]; idxS[tid] = idxf[tid]; }
    const float* h = out + OUT_H;
    for (int e = tid; e < 32768; e += 256) Hs[e >> 9][e & 511] = h[e];
    for (int e = tid; e < 4096; e += 256) {
        int g = row0 * 64 + e;
        Ws[e >> 6][e & 63] = wg * cwr_tm1[g] + (1.f - wg) + cwlu_tm1[g];
    }
    __syncthreads();
    if (tid < 64) {
        int gr = row0 + tid;
        float f = 1.f;
        for (int b = 0; b < 64; ++b) if (idxS[b] == gr) f = 0.f;
        keepf[tid] = f;
    }
    for (int e = tid; e < 4096; e += 256) {
        int g = row0 * 64 + e;
        out[OUT_CWLU + g] = (out[OUT_CWU + g] <= minS[e & 63]) ? 1.f : 0.f;
    }
    __syncthreads();
    const int warp = tid >> 6, lane = tid & 63;
    for (int r = warp * 16; r < warp * 16 + 16; ++r) {
        int grow = row0 + r;
        float kr = keepf[r];
        float acc[8];
        #pragma unroll
        for (int k = 0; k < 8; ++k)
            acc[k] = m_tm1[(size_t)grow * 512 + lane + 64*k] * kr;
        for (int b = 0; b < 64; ++b) {
            float w = Ws[r][b];
            #pragma unroll
            for (int k = 0; k < 8; ++k) acc[k] += w * Hs[b][lane + 64*k];
        }
        #pragma unroll
        for (int k = 0; k < 8; ++k)
            out[OUT_M + (size_t)grow * 512 + lane + 64*k] = acc[k];
    }
}

// ---------------------------------------------------------------------------
// K5: read = c_wr^T @ m_tm1, split-K over row blocks, f32 atomic accumulate
// ---------------------------------------------------------------------------
__global__ __launch_bounds__(256) void k_read(
    const float* __restrict__ m_tm1, const float* __restrict__ cwr,
    float* __restrict__ readout)
{
    __shared__ float Ws[64][65];
    const int blk = blockIdx.x, tid = threadIdx.x, row0 = blk * 64;
    for (int e = tid; e < 4096; e += 256) Ws[e >> 6][e & 63] = cwr[row0 * 64 + e];
    __syncthreads();
    const int warp = tid >> 6, lane = tid & 63;
    const int b0 = warp * 16;
    for (int k = 0; k < 8; ++k) {
        int u = lane + (k << 6);
        float acc[16] = {};
        for (int r = 0; r < 64; ++r) {
            float mv = m_tm1[(size_t)(row0 + r) * 512 + u];
            #pragma unroll
            for (int bb = 0; bb < 16; ++bb) acc[bb] += Ws[r][b0 + bb] * mv;
        }
        #pragma unroll
        for (int bb = 0; bb < 16; ++bb)
            atomicAdd(&readout[(b0 + bb) * 512 + u], acc[bb]);
    }
}

extern "C" void kernel_launch(void* const* d_in, const int* in_sizes, int n_in,
                              void* d_out, int out_size, void* d_ws, size_t ws_size,
                              hipStream_t stream)
{
    const float* inputs    = (const float*)d_in[0];
    const float* h_tm1     = (const float*)d_in[1];
    const float* c_tm1     = (const float*)d_in[2];
    const float* r_tm1     = (const float*)d_in[3];
    const float* m_tm1     = (const float*)d_in[4];
    const float* c_wu_tm1  = (const float*)d_in[5];
    const float* c_wlu_tm1 = (const float*)d_in[6];
    const float* c_wr_tm1  = (const float*)d_in[7];
    const float* wk        = (const float*)d_in[8];
    const float* rk        = (const float*)d_in[9];
    const float* bias      = (const float*)d_in[10];
    const float* wgate     = (const float*)d_in[11];
    float* out = (float*)d_out;
    float* ws  = (float*)d_ws;

    // zero read region for atomic split-K accumulation
    hipMemsetAsync((char*)d_out + (size_t)OUT_READ * sizeof(float), 0,
                   (size_t)32768 * sizeof(float), stream);

    k_preact<<<144, 256, 0, stream>>>(inputs, h_tm1, r_tm1, wk, rk, ws + WS_PRE);
    k_gates<<<128, 256, 0, stream>>>(ws + WS_PRE, bias, c_tm1, out);
    k_nkey<<<64, 256, 0, stream>>>(out + OUT_H, ws + WS_NKEY);
    k_cos<<<256, 256, 0, stream>>>(m_tm1, ws + WS_NKEY, c_wr_tm1, c_wlu_tm1,
                                   c_wu_tm1, wgate, out, ws + WS_PMIN,
                                   (int*)(ws + WS_PIDX));
    k_minfinal<<<1, 64, 0, stream>>>(ws + WS_PMIN, (const int*)(ws + WS_PIDX),
                                     ws + WS_MINF, (int*)(ws + WS_IDXF));
    k_update<<<256, 256, 0, stream>>>(m_tm1, c_wr_tm1, c_wlu_tm1, wgate,
                                      ws + WS_MINF, (const int*)(ws + WS_IDXF), out);
    k_read<<<256, 256, 0, stream>>>(m_tm1, out + OUT_CWR, out + OUT_READ);
}

// Round 4
// 199.173 us; speedup vs baseline: 1.6249x; 1.6249x over previous
//
#include <hip/hip_runtime.h>
#include <math.h>

// Problem dims: UNITS=512, MEM=16384, BATCH=64
// d_out offsets (floats): h, c, read, m, c_wu, c_wlu, c_wr
#define OUT_H    0
#define OUT_C    32768
#define OUT_READ 65536
#define OUT_M    98304
#define OUT_CWU  8486912
#define OUT_CWLU 9535488
#define OUT_CWR  10584064

// Preactivation scratch lives in the OUT_M region (2*294912 = 589824 floats
// out of 8388608 available). k_gates consumes it before k_update overwrites m.
// ws offsets (floats) — total 65664 floats = 257 KB
#define WS_NKEY  0          // 512*64 normalized key^T (K-major)
#define WS_PMIN  32768      // 256*64 partial min values
#define WS_PIDX  49152      // 256*64 partial min indices (int)
#define WS_MINF  65536      // 64 final min
#define WS_IDXF  65600      // 64 final argmin (int)

__device__ __forceinline__ float hsig(float x) {
    return fminf(fmaxf(0.2f * x + 0.5f, 0.f), 1.f);
}

// ---------------------------------------------------------------------------
// K1: preactivations. Virtual col space 4608 = [x:2048 | hk:2048 | r_i:512]
// grid 144 = 72 col-tiles(64) x 2 K-halves(256). Block 256, thread 4r x 4c.
// ---------------------------------------------------------------------------
__global__ __launch_bounds__(256) void k_preact(
    const float* __restrict__ inputs, const float* __restrict__ h_tm1,
    const float* __restrict__ r_tm1, const float* __restrict__ wk,
    const float* __restrict__ rk, float* __restrict__ pre)
{
    __shared__ alignas(16) float Ast[32][68];   // [k][row 0..63 + pad]
    __shared__ alignas(16) float Bs[32][72];    // [k][col]
    const int cb = blockIdx.x % 72, kh = blockIdx.x / 72;
    const int vcol0 = cb * 64;
    const float* A; const float* W; int wstride, wcol0;
    if (vcol0 < 2048)      { A = inputs; W = wk; wstride = 2048; wcol0 = vcol0; }
    else if (vcol0 < 4096) { A = h_tm1;  W = rk; wstride = 2560; wcol0 = vcol0 - 2048; }
    else                   { A = r_tm1;  W = rk; wstride = 2560; wcol0 = 2048 + (vcol0 - 4096); }
    const int tid = threadIdx.x;
    const int rgrp = tid >> 4, cgrp = tid & 15;     // rows rgrp*4.., cols cgrp*4..
    const int srow = tid >> 2, sk = (tid & 3) * 4;  // A staging
    const int skk = tid >> 3, sc = (tid & 7) * 4;   // W staging
    float acc[4][4] = {};
    for (int t = 0; t < 8; ++t) {
        const int k0 = kh * 256 + t * 32;
        float4 a0 = *(const float4*)&A[srow * 512 + k0 + sk];
        float4 a1 = *(const float4*)&A[srow * 512 + k0 + 16 + sk];
        float4 w0 = *(const float4*)&W[(size_t)(k0 + skk) * wstride + wcol0 + sc];
        float4 w1 = *(const float4*)&W[(size_t)(k0 + skk) * wstride + wcol0 + 32 + sc];
        Ast[sk + 0][srow] = a0.x; Ast[sk + 1][srow] = a0.y;
        Ast[sk + 2][srow] = a0.z; Ast[sk + 3][srow] = a0.w;
        Ast[16 + sk + 0][srow] = a1.x; Ast[16 + sk + 1][srow] = a1.y;
        Ast[16 + sk + 2][srow] = a1.z; Ast[16 + sk + 3][srow] = a1.w;
        Bs[skk][sc + 0] = w0.x; Bs[skk][sc + 1] = w0.y;
        Bs[skk][sc + 2] = w0.z; Bs[skk][sc + 3] = w0.w;
        Bs[skk][32 + sc + 0] = w1.x; Bs[skk][32 + sc + 1] = w1.y;
        Bs[skk][32 + sc + 2] = w1.z; Bs[skk][32 + sc + 3] = w1.w;
        __syncthreads();
        #pragma unroll
        for (int kk = 0; kk < 32; ++kk) {
            float4 av = *(const float4*)&Ast[kk][rgrp * 4];
            float4 bv = *(const float4*)&Bs[kk][cgrp * 4];
            acc[0][0] += av.x * bv.x; acc[0][1] += av.x * bv.y; acc[0][2] += av.x * bv.z; acc[0][3] += av.x * bv.w;
            acc[1][0] += av.y * bv.x; acc[1][1] += av.y * bv.y; acc[1][2] += av.y * bv.z; acc[1][3] += av.y * bv.w;
            acc[2][0] += av.z * bv.x; acc[2][1] += av.z * bv.y; acc[2][2] += av.z * bv.z; acc[2][3] += av.z * bv.w;
            acc[3][0] += av.w * bv.x; acc[3][1] += av.w * bv.y; acc[3][2] += av.w * bv.z; acc[3][3] += av.w * bv.w;
        }
        __syncthreads();
    }
    float* dst = pre + (size_t)kh * 294912;
    #pragma unroll
    for (int i = 0; i < 4; ++i) {
        float4 v = { acc[i][0], acc[i][1], acc[i][2], acc[i][3] };
        *(float4*)&dst[(rgrp * 4 + i) * 4608 + vcol0 + cgrp * 4] = v;
    }
}

// ---------------------------------------------------------------------------
// K1c: gate fusion (sums the two K-halves) -> h, c
// ---------------------------------------------------------------------------
__global__ __launch_bounds__(256) void k_gates(
    const float* __restrict__ pre, const float* __restrict__ bias,
    const float* __restrict__ c_tm1, float* __restrict__ out)
{
    int idx = blockIdx.x * 256 + threadIdx.x;   // 32768
    int b = idx >> 9, u = idx & 511;
    const float* p0 = pre + b * 4608;
    const float* p1 = pre + 294912 + b * 4608;
    float xi = p0[u]        + p1[u]        + bias[u];
    float xf = p0[512 + u]  + p1[512 + u]  + bias[512 + u];
    float xc = p0[1024 + u] + p1[1024 + u] + bias[1024 + u];
    float xo = p0[1536 + u] + p1[1536 + u] + bias[1536 + u];
    float hi = p0[2048 + u] + p1[2048 + u];
    float hf = p0[2560 + u] + p1[2560 + u];
    float hc = p0[3072 + u] + p1[3072 + u];
    float ho = p0[3584 + u] + p1[3584 + u];
    float ri = p0[4096 + u] + p1[4096 + u];
    float ig = hsig(xi + hi + ri);
    float fg = hsig(xf + hf);
    float cc = fg * c_tm1[idx] + ig * tanhf(xc + hc);
    float og = hsig(xo + ho);
    float hh = og * tanhf(cc);
    out[OUT_H + idx] = hh;
    out[OUT_C + idx] = cc;
}

// ---------------------------------------------------------------------------
// K1b: n_key^T (K-major, 512 x 64): per-batch L2 normalization of h
// ---------------------------------------------------------------------------
__global__ __launch_bounds__(256) void k_nkey(
    const float* __restrict__ h, float* __restrict__ nkeyT)
{
    int b = blockIdx.x, t = threadIdx.x;
    float v0 = h[b * 512 + t];
    float v1 = h[b * 512 + 256 + t];
    float ss = v0 * v0 + v1 * v1;
    __shared__ float red[4];
    for (int m = 1; m < 64; m <<= 1) ss += __shfl_xor(ss, m);
    if ((t & 63) == 0) red[t >> 6] = ss;
    __syncthreads();
    float tot = red[0] + red[1] + red[2] + red[3];
    float rn = rsqrtf(fmaxf(tot, 1e-12f));
    nkeyT[t * 64 + b]         = v0 * rn;
    nkeyT[(256 + t) * 64 + b] = v1 * rn;
}

// ---------------------------------------------------------------------------
// K2: cos GEMM 64 rows/block (grid 256), thread 4r x 4c.
// A (m-tile) transposed in LDS (b128 reads); B (nkey) from global (L2-hot).
// Fused: row-norm, softmax over batch, c_ww/c_wu, column min/argmin partials.
// ---------------------------------------------------------------------------
__global__ __launch_bounds__(256) void k_cos(
    const float* __restrict__ m_tm1, const float* __restrict__ nkeyT,
    const float* __restrict__ cwr_tm1, const float* __restrict__ cwlu_tm1,
    const float* __restrict__ cwu_tm1, const float* __restrict__ wgp,
    float* out, float* __restrict__ pmin, int* __restrict__ pidx)
{
    __shared__ alignas(16) float Ast[32][68];   // [k][row 0..63 + pad]
    __shared__ float rn[64];
    __shared__ alignas(16) float pmv[16][64];
    __shared__ alignas(16) int   pmi[16][64];
    const int row0 = blockIdx.x * 64;
    const int tid = threadIdx.x;
    const int rgrp = tid >> 4, cgrp = tid & 15;     // rows rgrp*4.., cols cgrp*4..
    const int srow = tid >> 2, sk = (tid & 3) * 4;  // staging: row, k-slot
    float acc[4][4] = {};
    float ssp = 0.f;
    for (int t = 0; t < 16; ++t) {
        const int k0 = t * 32;
        float4 a0 = *(const float4*)&m_tm1[(size_t)(row0 + srow) * 512 + k0 + sk];
        float4 a1 = *(const float4*)&m_tm1[(size_t)(row0 + srow) * 512 + k0 + 16 + sk];
        ssp += a0.x * a0.x + a0.y * a0.y + a0.z * a0.z + a0.w * a0.w;
        ssp += a1.x * a1.x + a1.y * a1.y + a1.z * a1.z + a1.w * a1.w;
        Ast[sk + 0][srow] = a0.x; Ast[sk + 1][srow] = a0.y;
        Ast[sk + 2][srow] = a0.z; Ast[sk + 3][srow] = a0.w;
        Ast[16 + sk + 0][srow] = a1.x; Ast[16 + sk + 1][srow] = a1.y;
        Ast[16 + sk + 2][srow] = a1.z; Ast[16 + sk + 3][srow] = a1.w;
        __syncthreads();
        #pragma unroll
        for (int kk = 0; kk < 32; ++kk) {
            float4 av = *(const float4*)&Ast[kk][rgrp * 4];
            float4 bv = *(const float4*)&nkeyT[(k0 + kk) * 64 + cgrp * 4];
            acc[0][0] += av.x * bv.x; acc[0][1] += av.x * bv.y; acc[0][2] += av.x * bv.z; acc[0][3] += av.x * bv.w;
            acc[1][0] += av.y * bv.x; acc[1][1] += av.y * bv.y; acc[1][2] += av.y * bv.z; acc[1][3] += av.y * bv.w;
            acc[2][0] += av.z * bv.x; acc[2][1] += av.z * bv.y; acc[2][2] += av.z * bv.z; acc[2][3] += av.z * bv.w;
            acc[3][0] += av.w * bv.x; acc[3][1] += av.w * bv.y; acc[3][2] += av.w * bv.z; acc[3][3] += av.w * bv.w;
        }
        __syncthreads();
    }
    // row sumsq: reduce across the 4 staging k-slots (lanes tid&3)
    ssp += __shfl_xor(ssp, 1);
    ssp += __shfl_xor(ssp, 2);
    if ((tid & 3) == 0) rn[srow] = ssp;
    __syncthreads();

    const float wg = 1.f / (1.f + expf(-wgp[0]));
    float p[4][4];
    #pragma unroll
    for (int i = 0; i < 4; ++i) {
        float rsq = rsqrtf(fmaxf(rn[rgrp * 4 + i], 1e-12f));
        float c0 = acc[i][0] * rsq, c1 = acc[i][1] * rsq;
        float c2 = acc[i][2] * rsq, c3 = acc[i][3] * rsq;
        // softmax over 64 cols; row's 16 threads are a contiguous 16-lane group
        float mx = fmaxf(fmaxf(c0, c1), fmaxf(c2, c3));
        mx = fmaxf(mx, __shfl_xor(mx, 1));
        mx = fmaxf(mx, __shfl_xor(mx, 2));
        mx = fmaxf(mx, __shfl_xor(mx, 4));
        mx = fmaxf(mx, __shfl_xor(mx, 8));
        float e0 = expf(c0 - mx), e1 = expf(c1 - mx), e2 = expf(c2 - mx), e3 = expf(c3 - mx);
        float sm = e0 + e1 + e2 + e3;
        sm += __shfl_xor(sm, 1);
        sm += __shfl_xor(sm, 2);
        sm += __shfl_xor(sm, 4);
        sm += __shfl_xor(sm, 8);
        float inv = 1.f / sm;
        p[i][0] = e0 * inv; p[i][1] = e1 * inv; p[i][2] = e2 * inv; p[i][3] = e3 * inv;
    }
    const int colbase = cgrp * 4;
    float bmv[4] = { INFINITY, INFINITY, INFINITY, INFINITY };
    int bmi[4] = { 0, 0, 0, 0 };
    #pragma unroll
    for (int i = 0; i < 4; ++i) {
        int grow = row0 + rgrp * 4 + i;
        int g = grow * 64 + colbase;
        float4 pr = { p[i][0], p[i][1], p[i][2], p[i][3] };
        *(float4*)&out[OUT_CWR + g] = pr;
        float4 wr = *(const float4*)&cwr_tm1[g];
        float4 wl = *(const float4*)&cwlu_tm1[g];
        float4 wu = *(const float4*)&cwu_tm1[g];
        float4 cwu;
        cwu.x = 0.95f * wu.x + pr.x + (wg * wr.x + (1.f - wg) + wl.x);
        cwu.y = 0.95f * wu.y + pr.y + (wg * wr.y + (1.f - wg) + wl.y);
        cwu.z = 0.95f * wu.z + pr.z + (wg * wr.z + (1.f - wg) + wl.z);
        cwu.w = 0.95f * wu.w + pr.w + (wg * wr.w + (1.f - wg) + wl.w);
        *(float4*)&out[OUT_CWU + g] = cwu;
        if (cwu.x < bmv[0]) { bmv[0] = cwu.x; bmi[0] = grow; }
        if (cwu.y < bmv[1]) { bmv[1] = cwu.y; bmi[1] = grow; }
        if (cwu.z < bmv[2]) { bmv[2] = cwu.z; bmi[2] = grow; }
        if (cwu.w < bmv[3]) { bmv[3] = cwu.w; bmi[3] = grow; }
    }
    #pragma unroll
    for (int j = 0; j < 4; ++j) { pmv[rgrp][colbase + j] = bmv[j]; pmi[rgrp][colbase + j] = bmi[j]; }
    __syncthreads();
    if (tid < 64) {
        float bv = INFINITY; int bi = 0x7fffffff;
        #pragma unroll
        for (int rg = 0; rg < 16; ++rg) {
            float v = pmv[rg][tid];
            if (v < bv) { bv = v; bi = pmi[rg][tid]; }
        }
        pmin[blockIdx.x * 64 + tid] = bv;
        pidx[blockIdx.x * 64 + tid] = bi;
    }
}

// ---------------------------------------------------------------------------
// K3: final min/argmin reduce (first-occurrence semantics like jnp.argmin)
// ---------------------------------------------------------------------------
__global__ __launch_bounds__(256) void k_minfinal(
    const float* __restrict__ pmin, const int* __restrict__ pidx,
    float* __restrict__ minf, int* __restrict__ idxf)
{
    __shared__ float fv[4][64];
    __shared__ int   fi[4][64];
    const int part = threadIdx.x >> 6, col = threadIdx.x & 63;
    float bv = INFINITY; int bi = 0x7fffffff;
    for (int q = 0; q < 64; ++q) {
        int pp = part * 64 + q;
        float v = pmin[pp * 64 + col];
        int   i = pidx[pp * 64 + col];
        if (v < bv || (v == bv && i < bi)) { bv = v; bi = i; }
    }
    fv[part][col] = bv; fi[part][col] = bi;
    __syncthreads();
    if (threadIdx.x < 64) {
        float v = fv[0][threadIdx.x]; int i = fi[0][threadIdx.x];
        #pragma unroll
        for (int q = 1; q < 4; ++q) {
            float v2 = fv[q][threadIdx.x]; int i2 = fi[q][threadIdx.x];
            if (v2 < v || (v2 == v && i2 < i)) { v = v2; i = i2; }
        }
        minf[threadIdx.x] = v; idxf[threadIdx.x] = i;
    }
}

// ---------------------------------------------------------------------------
// K4: c_wlu compare + keep mask + m = m_tm1*keep + c_ww @ h (K=64)
// grid 1024 = 256 row-blocks(64) x 4 u-splits(128). Thread 8r x 4u.
// ---------------------------------------------------------------------------
__global__ __launch_bounds__(256) void k_update(
    const float* __restrict__ m_tm1, const float* __restrict__ cwr_tm1,
    const float* __restrict__ cwlu_tm1, const float* __restrict__ wgp,
    const float* __restrict__ minf, const int* __restrict__ idxf,
    float* out)
{
    __shared__ alignas(16) float Wst[64][68];   // c_ww transposed [b][r]
    __shared__ float keepf[64];
    __shared__ float minS[64];
    __shared__ int   idxS[64];
    const int rb = blockIdx.x >> 2, us = blockIdx.x & 3;
    const int row0 = rb * 64, u0 = us * 128;
    const int tid = threadIdx.x;
    const int rgrp = tid >> 5, cgrp = tid & 31;   // rows rgrp*8.., u = u0+cgrp*4
    if (tid < 64) { idxS[tid] = idxf[tid]; minS[tid] = minf[tid]; }
    __syncthreads();
    const float wg = 1.f / (1.f + expf(-wgp[0]));
    #pragma unroll
    for (int q = 0; q < 4; ++q) {
        int idx = q * 1024 + tid * 4;
        int r = idx >> 6, b = idx & 63;
        int g = (row0 + r) * 64 + b;
        float4 wr = *(const float4*)&cwr_tm1[g];
        float4 wl = *(const float4*)&cwlu_tm1[g];
        Wst[b + 0][r] = wg * wr.x + (1.f - wg) + wl.x;
        Wst[b + 1][r] = wg * wr.y + (1.f - wg) + wl.y;
        Wst[b + 2][r] = wg * wr.z + (1.f - wg) + wl.z;
        Wst[b + 3][r] = wg * wr.w + (1.f - wg) + wl.w;
    }
    if (tid < 64) {
        int gr = row0 + tid;
        float f = 1.f;
        #pragma unroll
        for (int b = 0; b < 64; ++b) if (idxS[b] == gr) f = 0.f;
        keepf[tid] = f;
    }
    __syncthreads();
    if (us == 0) {
        #pragma unroll
        for (int q = 0; q < 4; ++q) {
            int idx = q * 1024 + tid * 4;
            int r = idx >> 6, b = idx & 63;
            int g = (row0 + r) * 64 + b;
            float4 cu = *(const float4*)&out[OUT_CWU + g];
            float4 res;
            res.x = (cu.x <= minS[b + 0]) ? 1.f : 0.f;
            res.y = (cu.y <= minS[b + 1]) ? 1.f : 0.f;
            res.z = (cu.z <= minS[b + 2]) ? 1.f : 0.f;
            res.w = (cu.w <= minS[b + 3]) ? 1.f : 0.f;
            *(float4*)&out[OUT_CWLU + g] = res;
        }
    }
    float4 acc[8];
    #pragma unroll
    for (int i = 0; i < 8; ++i) {
        int row = rgrp * 8 + i;
        float kf = keepf[row];
        float4 mv = *(const float4*)&m_tm1[(size_t)(row0 + row) * 512 + u0 + cgrp * 4];
        acc[i].x = mv.x * kf; acc[i].y = mv.y * kf; acc[i].z = mv.z * kf; acc[i].w = mv.w * kf;
    }
    for (int b = 0; b < 64; ++b) {
        float4 w1 = *(const float4*)&Wst[b][rgrp * 8];
        float4 w2 = *(const float4*)&Wst[b][rgrp * 8 + 4];
        float4 hv = *(const float4*)&out[OUT_H + b * 512 + u0 + cgrp * 4];
        acc[0].x += w1.x * hv.x; acc[0].y += w1.x * hv.y; acc[0].z += w1.x * hv.z; acc[0].w += w1.x * hv.w;
        acc[1].x += w1.y * hv.x; acc[1].y += w1.y * hv.y; acc[1].z += w1.y * hv.z; acc[1].w += w1.y * hv.w;
        acc[2].x += w1.z * hv.x; acc[2].y += w1.z * hv.y; acc[2].z += w1.z * hv.z; acc[2].w += w1.z * hv.w;
        acc[3].x += w1.w * hv.x; acc[3].y += w1.w * hv.y; acc[3].z += w1.w * hv.z; acc[3].w += w1.w * hv.w;
        acc[4].x += w2.x * hv.x; acc[4].y += w2.x * hv.y; acc[4].z += w2.x * hv.z; acc[4].w += w2.x * hv.w;
        acc[5].x += w2.y * hv.x; acc[5].y += w2.y * hv.y; acc[5].z += w2.y * hv.z; acc[5].w += w2.y * hv.w;
        acc[6].x += w2.z * hv.x; acc[6].y += w2.z * hv.y; acc[6].z += w2.z * hv.z; acc[6].w += w2.z * hv.w;
        acc[7].x += w2.w * hv.x; acc[7].y += w2.w * hv.y; acc[7].z += w2.w * hv.z; acc[7].w += w2.w * hv.w;
    }
    #pragma unroll
    for (int i = 0; i < 8; ++i) {
        int row = rgrp * 8 + i;
        *(float4*)&out[OUT_M + (size_t)(row0 + row) * 512 + u0 + cgrp * 4] = acc[i];
    }
}

// ---------------------------------------------------------------------------
// K5: read = c_wr^T @ m_tm1. grid 512 = 64 row-splits(256) x 8 u-splits(64).
// m chunks in LDS (natural layout), cwr broadcast from global, f32 atomics.
// ---------------------------------------------------------------------------
__global__ __launch_bounds__(256) void k_read(
    const float* __restrict__ m_tm1, const float* __restrict__ cwr,
    float* __restrict__ readout)
{
    __shared__ alignas(16) float Ms[64][64];
    const int rb = blockIdx.x >> 3, us = blockIdx.x & 7;
    const int row0 = rb * 256, u0 = us * 64;
    const int tid = threadIdx.x;
    const int bgrp = tid >> 5, ugrp = tid & 31;   // b0 = bgrp*8, u = u0+ugrp*2
    const int b0 = bgrp * 8;
    float2 acc[8] = {};
    for (int ch = 0; ch < 4; ++ch) {
        const int r0 = row0 + ch * 64;
        #pragma unroll
        for (int rr = 0; rr < 4; ++rr) {
            int row = rr * 16 + (tid >> 4);
            int c = (tid & 15) * 4;
            *(float4*)&Ms[row][c] = *(const float4*)&m_tm1[(size_t)(r0 + row) * 512 + u0 + c];
        }
        __syncthreads();
        for (int r = 0; r < 64; ++r) {
            int grow = r0 + r;
            float4 w1 = *(const float4*)&cwr[grow * 64 + b0];
            float4 w2 = *(const float4*)&cwr[grow * 64 + b0 + 4];
            float2 mv = *(const float2*)&Ms[r][ugrp * 2];
            acc[0].x += w1.x * mv.x; acc[0].y += w1.x * mv.y;
            acc[1].x += w1.y * mv.x; acc[1].y += w1.y * mv.y;
            acc[2].x += w1.z * mv.x; acc[2].y += w1.z * mv.y;
            acc[3].x += w1.w * mv.x; acc[3].y += w1.w * mv.y;
            acc[4].x += w2.x * mv.x; acc[4].y += w2.x * mv.y;
            acc[5].x += w2.y * mv.x; acc[5].y += w2.y * mv.y;
            acc[6].x += w2.z * mv.x; acc[6].y += w2.z * mv.y;
            acc[7].x += w2.w * mv.x; acc[7].y += w2.w * mv.y;
        }
        __syncthreads();
    }
    #pragma unroll
    for (int bb = 0; bb < 8; ++bb) {
        int u = u0 + ugrp * 2;
        atomicAdd(&readout[(b0 + bb) * 512 + u],     acc[bb].x);
        atomicAdd(&readout[(b0 + bb) * 512 + u + 1], acc[bb].y);
    }
}

extern "C" void kernel_launch(void* const* d_in, const int* in_sizes, int n_in,
                              void* d_out, int out_size, void* d_ws, size_t ws_size,
                              hipStream_t stream)
{
    const float* inputs    = (const float*)d_in[0];
    const float* h_tm1     = (const float*)d_in[1];
    const float* c_tm1     = (const float*)d_in[2];
    const float* r_tm1     = (const float*)d_in[3];
    const float* m_tm1     = (const float*)d_in[4];
    const float* c_wu_tm1  = (const float*)d_in[5];
    const float* c_wlu_tm1 = (const float*)d_in[6];
    const float* c_wr_tm1  = (const float*)d_in[7];
    const float* wk        = (const float*)d_in[8];
    const float* rk        = (const float*)d_in[9];
    const float* bias      = (const float*)d_in[10];
    const float* wgate     = (const float*)d_in[11];
    float* out = (float*)d_out;
    float* ws  = (float*)d_ws;
    float* pre = out + OUT_M;   // scratch inside OUT_M region; consumed by
                                // k_gates before k_update overwrites m.

    // zero read region for atomic split-K accumulation
    hipMemsetAsync((char*)d_out + (size_t)OUT_READ * sizeof(float), 0,
                   (size_t)32768 * sizeof(float), stream);

    k_preact<<<144, 256, 0, stream>>>(inputs, h_tm1, r_tm1, wk, rk, pre);
    k_gates<<<128, 256, 0, stream>>>(pre, bias, c_tm1, out);
    k_nkey<<<64, 256, 0, stream>>>(out + OUT_H, ws + WS_NKEY);
    k_cos<<<256, 256, 0, stream>>>(m_tm1, ws + WS_NKEY, c_wr_tm1, c_wlu_tm1,
                                   c_wu_tm1, wgate, out, ws + WS_PMIN,
                                   (int*)(ws + WS_PIDX));
    k_minfinal<<<1, 256, 0, stream>>>(ws + WS_PMIN, (const int*)(ws + WS_PIDX),
                                      ws + WS_MINF, (int*)(ws + WS_IDXF));
    k_update<<<1024, 256, 0, stream>>>(m_tm1, c_wr_tm1, c_wlu_tm1, wgate,
                                       ws + WS_MINF, (const int*)(ws + WS_IDXF), out);
    k_read<<<512, 256, 0, stream>>>(m_tm1, out + OUT_CWR, out + OUT_READ);
}

// Round 5
// 124.734 us; speedup vs baseline: 2.5946x; 1.5968x over previous
//
#include <hip/hip_runtime.h>
#include <math.h>

// Problem dims: UNITS=512, MEM=16384, BATCH=64
// d_out offsets (floats): h, c, read, m, c_wu, c_wlu, c_wr
#define OUT_H    0
#define OUT_C    32768
#define OUT_READ 65536
#define OUT_M    98304
#define OUT_CWU  8486912
#define OUT_CWLU 9535488
#define OUT_CWR  10584064

// Scratch inside OUT_M region (8.4M floats), consumed before k_update
// overwrites m: preact 589824 floats; read-partials 4M floats.
// ws offsets (floats) — total 65664 floats = 257 KB
#define WS_NKEY  0          // 512*64 normalized key^T (K-major)
#define WS_PMIN  32768      // 256*64 partial min values
#define WS_PIDX  49152      // 256*64 partial min indices (int)
#define WS_MINF  65536      // 64 final min
#define WS_IDXF  65600      // 64 final argmin (int)

__device__ __forceinline__ float hsig(float x) {
    return fminf(fmaxf(0.2f * x + 0.5f, 0.f), 1.f);
}

// ---------------------------------------------------------------------------
// K1: preactivations. Virtual col space 4608 = [x:2048 | hk:2048 | r_i:512]
// grid 144 = 72 col-tiles(64) x 2 K-halves(256). Block 256, thread 4r x 4c.
// ---------------------------------------------------------------------------
__global__ __launch_bounds__(256) void k_preact(
    const float* __restrict__ inputs, const float* __restrict__ h_tm1,
    const float* __restrict__ r_tm1, const float* __restrict__ wk,
    const float* __restrict__ rk, float* __restrict__ pre)
{
    __shared__ alignas(16) float Ast[32][68];   // [k][row 0..63 + pad]
    __shared__ alignas(16) float Bs[32][72];    // [k][col]
    const int cb = blockIdx.x % 72, kh = blockIdx.x / 72;
    const int vcol0 = cb * 64;
    const float* A; const float* W; int wstride, wcol0;
    if (vcol0 < 2048)      { A = inputs; W = wk; wstride = 2048; wcol0 = vcol0; }
    else if (vcol0 < 4096) { A = h_tm1;  W = rk; wstride = 2560; wcol0 = vcol0 - 2048; }
    else                   { A = r_tm1;  W = rk; wstride = 2560; wcol0 = 2048 + (vcol0 - 4096); }
    const int tid = threadIdx.x;
    const int rgrp = tid >> 4, cgrp = tid & 15;     // rows rgrp*4.., cols cgrp*4..
    const int srow = tid >> 2, sk = (tid & 3) * 4;  // A staging
    const int skk = tid >> 3, sc = (tid & 7) * 4;   // W staging
    float acc[4][4] = {};
    for (int t = 0; t < 8; ++t) {
        const int k0 = kh * 256 + t * 32;
        float4 a0 = *(const float4*)&A[srow * 512 + k0 + sk];
        float4 a1 = *(const float4*)&A[srow * 512 + k0 + 16 + sk];
        float4 w0 = *(const float4*)&W[(size_t)(k0 + skk) * wstride + wcol0 + sc];
        float4 w1 = *(const float4*)&W[(size_t)(k0 + skk) * wstride + wcol0 + 32 + sc];
        Ast[sk + 0][srow] = a0.x; Ast[sk + 1][srow] = a0.y;
        Ast[sk + 2][srow] = a0.z; Ast[sk + 3][srow] = a0.w;
        Ast[16 + sk + 0][srow] = a1.x; Ast[16 + sk + 1][srow] = a1.y;
        Ast[16 + sk + 2][srow] = a1.z; Ast[16 + sk + 3][srow] = a1.w;
        Bs[skk][sc + 0] = w0.x; Bs[skk][sc + 1] = w0.y;
        Bs[skk][sc + 2] = w0.z; Bs[skk][sc + 3] = w0.w;
        Bs[skk][32 + sc + 0] = w1.x; Bs[skk][32 + sc + 1] = w1.y;
        Bs[skk][32 + sc + 2] = w1.z; Bs[skk][32 + sc + 3] = w1.w;
        __syncthreads();
        #pragma unroll
        for (int kk = 0; kk < 32; ++kk) {
            float4 av = *(const float4*)&Ast[kk][rgrp * 4];
            float4 bv = *(const float4*)&Bs[kk][cgrp * 4];
            acc[0][0] += av.x * bv.x; acc[0][1] += av.x * bv.y; acc[0][2] += av.x * bv.z; acc[0][3] += av.x * bv.w;
            acc[1][0] += av.y * bv.x; acc[1][1] += av.y * bv.y; acc[1][2] += av.y * bv.z; acc[1][3] += av.y * bv.w;
            acc[2][0] += av.z * bv.x; acc[2][1] += av.z * bv.y; acc[2][2] += av.z * bv.z; acc[2][3] += av.z * bv.w;
            acc[3][0] += av.w * bv.x; acc[3][1] += av.w * bv.y; acc[3][2] += av.w * bv.z; acc[3][3] += av.w * bv.w;
        }
        __syncthreads();
    }
    float* dst = pre + (size_t)kh * 294912;
    #pragma unroll
    for (int i = 0; i < 4; ++i) {
        float4 v = { acc[i][0], acc[i][1], acc[i][2], acc[i][3] };
        *(float4*)&dst[(rgrp * 4 + i) * 4608 + vcol0 + cgrp * 4] = v;
    }
}

// ---------------------------------------------------------------------------
// K1c: gate fusion (sums the two K-halves) -> h, c
// ---------------------------------------------------------------------------
__global__ __launch_bounds__(256) void k_gates(
    const float* __restrict__ pre, const float* __restrict__ bias,
    const float* __restrict__ c_tm1, float* __restrict__ out)
{
    int idx = blockIdx.x * 256 + threadIdx.x;   // 32768
    int b = idx >> 9, u = idx & 511;
    const float* p0 = pre + b * 4608;
    const float* p1 = pre + 294912 + b * 4608;
    float xi = p0[u]        + p1[u]        + bias[u];
    float xf = p0[512 + u]  + p1[512 + u]  + bias[512 + u];
    float xc = p0[1024 + u] + p1[1024 + u] + bias[1024 + u];
    float xo = p0[1536 + u] + p1[1536 + u] + bias[1536 + u];
    float hi = p0[2048 + u] + p1[2048 + u];
    float hf = p0[2560 + u] + p1[2560 + u];
    float hc = p0[3072 + u] + p1[3072 + u];
    float ho = p0[3584 + u] + p1[3584 + u];
    float ri = p0[4096 + u] + p1[4096 + u];
    float ig = hsig(xi + hi + ri);
    float fg = hsig(xf + hf);
    float cc = fg * c_tm1[idx] + ig * tanhf(xc + hc);
    float og = hsig(xo + ho);
    float hh = og * tanhf(cc);
    out[OUT_H + idx] = hh;
    out[OUT_C + idx] = cc;
}

// ---------------------------------------------------------------------------
// K1b: n_key^T (K-major, 512 x 64): per-batch L2 normalization of h
// ---------------------------------------------------------------------------
__global__ __launch_bounds__(256) void k_nkey(
    const float* __restrict__ h, float* __restrict__ nkeyT)
{
    int b = blockIdx.x, t = threadIdx.x;
    float v0 = h[b * 512 + t];
    float v1 = h[b * 512 + 256 + t];
    float ss = v0 * v0 + v1 * v1;
    __shared__ float red[4];
    for (int m = 1; m < 64; m <<= 1) ss += __shfl_xor(ss, m);
    if ((t & 63) == 0) red[t >> 6] = ss;
    __syncthreads();
    float tot = red[0] + red[1] + red[2] + red[3];
    float rn = rsqrtf(fmaxf(tot, 1e-12f));
    nkeyT[t * 64 + b]         = v0 * rn;
    nkeyT[(256 + t) * 64 + b] = v1 * rn;
}

// ---------------------------------------------------------------------------
// K2: cos GEMM 64 rows/block (grid 256), thread 4r x 4c.
// Both operands staged in LDS (m transposed; nkey tile). Fused: row-norm,
// softmax over batch, c_ww/c_wu, column min/argmin partials.
// ---------------------------------------------------------------------------
__global__ __launch_bounds__(256) void k_cos(
    const float* __restrict__ m_tm1, const float* __restrict__ nkeyT,
    const float* __restrict__ cwr_tm1, const float* __restrict__ cwlu_tm1,
    const float* __restrict__ cwu_tm1, const float* __restrict__ wgp,
    float* out, float* __restrict__ pmin, int* __restrict__ pidx)
{
    __shared__ alignas(16) float Ast[32][68];   // [k][row 0..63 + pad]
    __shared__ alignas(16) float Bst[32][64];   // [k][batch]
    __shared__ float rn[64];
    __shared__ alignas(16) float pmv[16][64];
    __shared__ alignas(16) int   pmi[16][64];
    const int row0 = blockIdx.x * 64;
    const int tid = threadIdx.x;
    const int rgrp = tid >> 4, cgrp = tid & 15;     // rows rgrp*4.., cols cgrp*4..
    const int srow = tid >> 2, sk = (tid & 3) * 4;  // A staging: row, k-slot
    const int skb = tid >> 3, scb = (tid & 7) * 8;  // B staging: k, col
    float acc[4][4] = {};
    float ssp = 0.f;
    for (int t = 0; t < 16; ++t) {
        const int k0 = t * 32;
        float4 a0 = *(const float4*)&m_tm1[(size_t)(row0 + srow) * 512 + k0 + sk];
        float4 a1 = *(const float4*)&m_tm1[(size_t)(row0 + srow) * 512 + k0 + 16 + sk];
        float4 b0v = *(const float4*)&nkeyT[(k0 + skb) * 64 + scb];
        float4 b1v = *(const float4*)&nkeyT[(k0 + skb) * 64 + scb + 4];
        ssp += a0.x * a0.x + a0.y * a0.y + a0.z * a0.z + a0.w * a0.w;
        ssp += a1.x * a1.x + a1.y * a1.y + a1.z * a1.z + a1.w * a1.w;
        Ast[sk + 0][srow] = a0.x; Ast[sk + 1][srow] = a0.y;
        Ast[sk + 2][srow] = a0.z; Ast[sk + 3][srow] = a0.w;
        Ast[16 + sk + 0][srow] = a1.x; Ast[16 + sk + 1][srow] = a1.y;
        Ast[16 + sk + 2][srow] = a1.z; Ast[16 + sk + 3][srow] = a1.w;
        *(float4*)&Bst[skb][scb]     = b0v;
        *(float4*)&Bst[skb][scb + 4] = b1v;
        __syncthreads();
        #pragma unroll
        for (int kk = 0; kk < 32; ++kk) {
            float4 av = *(const float4*)&Ast[kk][rgrp * 4];
            float4 bv = *(const float4*)&Bst[kk][cgrp * 4];
            acc[0][0] += av.x * bv.x; acc[0][1] += av.x * bv.y; acc[0][2] += av.x * bv.z; acc[0][3] += av.x * bv.w;
            acc[1][0] += av.y * bv.x; acc[1][1] += av.y * bv.y; acc[1][2] += av.y * bv.z; acc[1][3] += av.y * bv.w;
            acc[2][0] += av.z * bv.x; acc[2][1] += av.z * bv.y; acc[2][2] += av.z * bv.z; acc[2][3] += av.z * bv.w;
            acc[3][0] += av.w * bv.x; acc[3][1] += av.w * bv.y; acc[3][2] += av.w * bv.z; acc[3][3] += av.w * bv.w;
        }
        __syncthreads();
    }
    // row sumsq: reduce across the 4 staging k-slots (lanes tid&3)
    ssp += __shfl_xor(ssp, 1);
    ssp += __shfl_xor(ssp, 2);
    if ((tid & 3) == 0) rn[srow] = ssp;
    __syncthreads();

    const float wg = 1.f / (1.f + expf(-wgp[0]));
    float p[4][4];
    #pragma unroll
    for (int i = 0; i < 4; ++i) {
        float rsq = rsqrtf(fmaxf(rn[rgrp * 4 + i], 1e-12f));
        float c0 = acc[i][0] * rsq, c1 = acc[i][1] * rsq;
        float c2 = acc[i][2] * rsq, c3 = acc[i][3] * rsq;
        // softmax over 64 cols; row's 16 threads are a contiguous 16-lane group
        float mx = fmaxf(fmaxf(c0, c1), fmaxf(c2, c3));
        mx = fmaxf(mx, __shfl_xor(mx, 1));
        mx = fmaxf(mx, __shfl_xor(mx, 2));
        mx = fmaxf(mx, __shfl_xor(mx, 4));
        mx = fmaxf(mx, __shfl_xor(mx, 8));
        float e0 = expf(c0 - mx), e1 = expf(c1 - mx), e2 = expf(c2 - mx), e3 = expf(c3 - mx);
        float sm = e0 + e1 + e2 + e3;
        sm += __shfl_xor(sm, 1);
        sm += __shfl_xor(sm, 2);
        sm += __shfl_xor(sm, 4);
        sm += __shfl_xor(sm, 8);
        float inv = 1.f / sm;
        p[i][0] = e0 * inv; p[i][1] = e1 * inv; p[i][2] = e2 * inv; p[i][3] = e3 * inv;
    }
    const int colbase = cgrp * 4;
    float bmv[4] = { INFINITY, INFINITY, INFINITY, INFINITY };
    int bmi[4] = { 0, 0, 0, 0 };
    #pragma unroll
    for (int i = 0; i < 4; ++i) {
        int grow = row0 + rgrp * 4 + i;
        int g = grow * 64 + colbase;
        float4 pr = { p[i][0], p[i][1], p[i][2], p[i][3] };
        *(float4*)&out[OUT_CWR + g] = pr;
        float4 wr = *(const float4*)&cwr_tm1[g];
        float4 wl = *(const float4*)&cwlu_tm1[g];
        float4 wu = *(const float4*)&cwu_tm1[g];
        float4 cwu;
        cwu.x = 0.95f * wu.x + pr.x + (wg * wr.x + (1.f - wg) + wl.x);
        cwu.y = 0.95f * wu.y + pr.y + (wg * wr.y + (1.f - wg) + wl.y);
        cwu.z = 0.95f * wu.z + pr.z + (wg * wr.z + (1.f - wg) + wl.z);
        cwu.w = 0.95f * wu.w + pr.w + (wg * wr.w + (1.f - wg) + wl.w);
        *(float4*)&out[OUT_CWU + g] = cwu;
        if (cwu.x < bmv[0]) { bmv[0] = cwu.x; bmi[0] = grow; }
        if (cwu.y < bmv[1]) { bmv[1] = cwu.y; bmi[1] = grow; }
        if (cwu.z < bmv[2]) { bmv[2] = cwu.z; bmi[2] = grow; }
        if (cwu.w < bmv[3]) { bmv[3] = cwu.w; bmi[3] = grow; }
    }
    #pragma unroll
    for (int j = 0; j < 4; ++j) { pmv[rgrp][colbase + j] = bmv[j]; pmi[rgrp][colbase + j] = bmi[j]; }
    __syncthreads();
    if (tid < 64) {
        float bv = INFINITY; int bi = 0x7fffffff;
        #pragma unroll
        for (int rg = 0; rg < 16; ++rg) {
            float v = pmv[rg][tid];
            if (v < bv) { bv = v; bi = pmi[rg][tid]; }
        }
        pmin[blockIdx.x * 64 + tid] = bv;
        pidx[blockIdx.x * 64 + tid] = bi;
    }
}

// ---------------------------------------------------------------------------
// K3: final min/argmin reduce (first-occurrence semantics like jnp.argmin)
// ---------------------------------------------------------------------------
__global__ __launch_bounds__(256) void k_minfinal(
    const float* __restrict__ pmin, const int* __restrict__ pidx,
    float* __restrict__ minf, int* __restrict__ idxf)
{
    __shared__ float fv[4][64];
    __shared__ int   fi[4][64];
    const int part = threadIdx.x >> 6, col = threadIdx.x & 63;
    float bv = INFINITY; int bi = 0x7fffffff;
    for (int q = 0; q < 64; ++q) {
        int pp = part * 64 + q;
        float v = pmin[pp * 64 + col];
        int   i = pidx[pp * 64 + col];
        if (v < bv || (v == bv && i < bi)) { bv = v; bi = i; }
    }
    fv[part][col] = bv; fi[part][col] = bi;
    __syncthreads();
    if (threadIdx.x < 64) {
        float v = fv[0][threadIdx.x]; int i = fi[0][threadIdx.x];
        #pragma unroll
        for (int q = 1; q < 4; ++q) {
            float v2 = fv[q][threadIdx.x]; int i2 = fi[q][threadIdx.x];
            if (v2 < v || (v2 == v && i2 < i)) { v = v2; i = i2; }
        }
        minf[threadIdx.x] = v; idxf[threadIdx.x] = i;
    }
}

// ---------------------------------------------------------------------------
// K5a: read partials. read = c_wr^T @ m_tm1, split-K over 128 row-blocks(128)
// x 8 u-splits(64). Both operands staged in LDS; no atomics — partials to
// part[rs*32768 + b*512 + u] (16 MB scratch in OUT_M region).
// ---------------------------------------------------------------------------
__global__ __launch_bounds__(256) void k_read_part(
    const float* __restrict__ m_tm1, const float* __restrict__ cwr,
    float* __restrict__ part)
{
    __shared__ alignas(16) float Ms[64][64];
    __shared__ alignas(16) float Ws[64][64];
    const int rs = blockIdx.x >> 3, us = blockIdx.x & 7;
    const int row0 = rs * 128, u0 = us * 64;
    const int tid = threadIdx.x;
    const int bg = tid >> 5, ug = tid & 31;   // b0 = bg*8, u = u0+ug*2
    const int b0 = bg * 8;
    float2 acc[8] = {};
    for (int ch = 0; ch < 2; ++ch) {
        const int r0 = row0 + ch * 64;
        #pragma unroll
        for (int rr = 0; rr < 4; ++rr) {
            int row = rr * 16 + (tid >> 4);
            int c = (tid & 15) * 4;
            *(float4*)&Ms[row][c] = *(const float4*)&m_tm1[(size_t)(r0 + row) * 512 + u0 + c];
        }
        #pragma unroll
        for (int q = 0; q < 4; ++q) {
            int idx = q * 1024 + tid * 4;
            *(float4*)&Ws[idx >> 6][idx & 63] = *(const float4*)&cwr[r0 * 64 + idx];
        }
        __syncthreads();
        for (int r = 0; r < 64; ++r) {
            float4 w1 = *(const float4*)&Ws[r][b0];
            float4 w2 = *(const float4*)&Ws[r][b0 + 4];
            float2 mv = *(const float2*)&Ms[r][ug * 2];
            acc[0].x += w1.x * mv.x; acc[0].y += w1.x * mv.y;
            acc[1].x += w1.y * mv.x; acc[1].y += w1.y * mv.y;
            acc[2].x += w1.z * mv.x; acc[2].y += w1.z * mv.y;
            acc[3].x += w1.w * mv.x; acc[3].y += w1.w * mv.y;
            acc[4].x += w2.x * mv.x; acc[4].y += w2.x * mv.y;
            acc[5].x += w2.y * mv.x; acc[5].y += w2.y * mv.y;
            acc[6].x += w2.z * mv.x; acc[6].y += w2.z * mv.y;
            acc[7].x += w2.w * mv.x; acc[7].y += w2.w * mv.y;
        }
        __syncthreads();
    }
    #pragma unroll
    for (int bb = 0; bb < 8; ++bb) {
        *(float2*)&part[(size_t)rs * 32768 + (b0 + bb) * 512 + u0 + ug * 2] = acc[bb];
    }
}

// ---------------------------------------------------------------------------
// K5b: read final reduce over the 128 partials (deterministic order).
// ---------------------------------------------------------------------------
__global__ __launch_bounds__(256) void k_read_final(
    const float* __restrict__ part, float* __restrict__ readout)
{
    int gid = blockIdx.x * 256 + threadIdx.x;  // 32768
    float s = 0.f;
    #pragma unroll 8
    for (int rs = 0; rs < 128; ++rs) s += part[(size_t)rs * 32768 + gid];
    readout[gid] = s;
}

// ---------------------------------------------------------------------------
// K4: c_wlu compare + keep mask + m = m_tm1*keep + c_ww @ h (K=64)
// grid 1024 = 256 row-blocks(64) x 4 u-splits(128). Thread 8r x 4u.
// h slice staged in LDS; inner loop LDS-only.
// ---------------------------------------------------------------------------
__global__ __launch_bounds__(256) void k_update(
    const float* __restrict__ m_tm1, const float* __restrict__ cwr_tm1,
    const float* __restrict__ cwlu_tm1, const float* __restrict__ wgp,
    const float* __restrict__ minf, const int* __restrict__ idxf,
    float* out)
{
    __shared__ alignas(16) float Wst[64][68];   // c_ww transposed [b][r]
    __shared__ alignas(16) float Hs[64][128];   // h slice [b][u-128]
    __shared__ float keepf[64];
    __shared__ float minS[64];
    __shared__ int   idxS[64];
    const int rb = blockIdx.x >> 2, us = blockIdx.x & 3;
    const int row0 = rb * 64, u0 = us * 128;
    const int tid = threadIdx.x;
    const int rgrp = tid >> 5, cgrp = tid & 31;   // rows rgrp*8.., u = u0+cgrp*4
    if (tid < 64) { idxS[tid] = idxf[tid]; minS[tid] = minf[tid]; }
    __syncthreads();
    const float wg = 1.f / (1.f + expf(-wgp[0]));
    #pragma unroll
    for (int q = 0; q < 4; ++q) {
        int idx = q * 1024 + tid * 4;
        int r = idx >> 6, b = idx & 63;
        int g = (row0 + r) * 64 + b;
        float4 wr = *(const float4*)&cwr_tm1[g];
        float4 wl = *(const float4*)&cwlu_tm1[g];
        Wst[b + 0][r] = wg * wr.x + (1.f - wg) + wl.x;
        Wst[b + 1][r] = wg * wr.y + (1.f - wg) + wl.y;
        Wst[b + 2][r] = wg * wr.z + (1.f - wg) + wl.z;
        Wst[b + 3][r] = wg * wr.w + (1.f - wg) + wl.w;
    }
    #pragma unroll
    for (int q = 0; q < 8; ++q) {
        int idx = q * 1024 + tid * 4;
        int b = idx >> 7, c = idx & 127;
        *(float4*)&Hs[b][c] = *(const float4*)&out[OUT_H + b * 512 + u0 + c];
    }
    if (tid < 64) {
        int gr = row0 + tid;
        float f = 1.f;
        #pragma unroll
        for (int b = 0; b < 64; ++b) if (idxS[b] == gr) f = 0.f;
        keepf[tid] = f;
    }
    __syncthreads();
    if (us == 0) {
        #pragma unroll
        for (int q = 0; q < 4; ++q) {
            int idx = q * 1024 + tid * 4;
            int r = idx >> 6, b = idx & 63;
            int g = (row0 + r) * 64 + b;
            float4 cu = *(const float4*)&out[OUT_CWU + g];
            float4 res;
            res.x = (cu.x <= minS[b + 0]) ? 1.f : 0.f;
            res.y = (cu.y <= minS[b + 1]) ? 1.f : 0.f;
            res.z = (cu.z <= minS[b + 2]) ? 1.f : 0.f;
            res.w = (cu.w <= minS[b + 3]) ? 1.f : 0.f;
            *(float4*)&out[OUT_CWLU + g] = res;
        }
    }
    float4 acc[8];
    #pragma unroll
    for (int i = 0; i < 8; ++i) {
        int row = rgrp * 8 + i;
        float kf = keepf[row];
        float4 mv = *(const float4*)&m_tm1[(size_t)(row0 + row) * 512 + u0 + cgrp * 4];
        acc[i].x = mv.x * kf; acc[i].y = mv.y * kf; acc[i].z = mv.z * kf; acc[i].w = mv.w * kf;
    }
    for (int b = 0; b < 64; ++b) {
        float4 w1 = *(const float4*)&Wst[b][rgrp * 8];
        float4 w2 = *(const float4*)&Wst[b][rgrp * 8 + 4];
        float4 hv = *(const float4*)&Hs[b][cgrp * 4];
        acc[0].x += w1.x * hv.x; acc[0].y += w1.x * hv.y; acc[0].z += w1.x * hv.z; acc[0].w += w1.x * hv.w;
        acc[1].x += w1.y * hv.x; acc[1].y += w1.y * hv.y; acc[1].z += w1.y * hv.z; acc[1].w += w1.y * hv.w;
        acc[2].x += w1.z * hv.x; acc[2].y += w1.z * hv.y; acc[2].z += w1.z * hv.z; acc[2].w += w1.z * hv.w;
        acc[3].x += w1.w * hv.x; acc[3].y += w1.w * hv.y; acc[3].z += w1.w * hv.z; acc[3].w += w1.w * hv.w;
        acc[4].x += w2.x * hv.x; acc[4].y += w2.x * hv.y; acc[4].z += w2.x * hv.z; acc[4].w += w2.x * hv.w;
        acc[5].x += w2.y * hv.x; acc[5].y += w2.y * hv.y; acc[5].z += w2.y * hv.z; acc[5].w += w2.y * hv.w;
        acc[6].x += w2.z * hv.x; acc[6].y += w2.z * hv.y; acc[6].z += w2.z * hv.z; acc[6].w += w2.z * hv.w;
        acc[7].x += w2.w * hv.x; acc[7].y += w2.w * hv.y; acc[7].z += w2.w * hv.z; acc[7].w += w2.w * hv.w;
    }
    #pragma unroll
    for (int i = 0; i < 8; ++i) {
        int row = rgrp * 8 + i;
        *(float4*)&out[OUT_M + (size_t)(row0 + row) * 512 + u0 + cgrp * 4] = acc[i];
    }
}

extern "C" void kernel_launch(void* const* d_in, const int* in_sizes, int n_in,
                              void* d_out, int out_size, void* d_ws, size_t ws_size,
                              hipStream_t stream)
{
    const float* inputs    = (const float*)d_in[0];
    const float* h_tm1     = (const float*)d_in[1];
    const float* c_tm1     = (const float*)d_in[2];
    const float* r_tm1     = (const float*)d_in[3];
    const float* m_tm1     = (const float*)d_in[4];
    const float* c_wu_tm1  = (const float*)d_in[5];
    const float* c_wlu_tm1 = (const float*)d_in[6];
    const float* c_wr_tm1  = (const float*)d_in[7];
    const float* wk        = (const float*)d_in[8];
    const float* rk        = (const float*)d_in[9];
    const float* bias      = (const float*)d_in[10];
    const float* wgate     = (const float*)d_in[11];
    float* out = (float*)d_out;
    float* ws  = (float*)d_ws;
    float* pre   = out + OUT_M;   // scratch in OUT_M region; consumed by k_gates
    float* rpart = out + OUT_M;   // reused after gates: read partials (4M floats)

    k_preact<<<144, 256, 0, stream>>>(inputs, h_tm1, r_tm1, wk, rk, pre);
    k_gates<<<128, 256, 0, stream>>>(pre, bias, c_tm1, out);
    k_nkey<<<64, 256, 0, stream>>>(out + OUT_H, ws + WS_NKEY);
    k_cos<<<256, 256, 0, stream>>>(m_tm1, ws + WS_NKEY, c_wr_tm1, c_wlu_tm1,
                                   c_wu_tm1, wgate, out, ws + WS_PMIN,
                                   (int*)(ws + WS_PIDX));
    k_minfinal<<<1, 256, 0, stream>>>(ws + WS_PMIN, (const int*)(ws + WS_PIDX),
                                      ws + WS_MINF, (int*)(ws + WS_IDXF));
    k_read_part<<<1024, 256, 0, stream>>>(m_tm1, out + OUT_CWR, rpart);
    k_read_final<<<128, 256, 0, stream>>>(rpart, out + OUT_READ);
    k_update<<<1024, 256, 0, stream>>>(m_tm1, c_wr_tm1, c_wlu_tm1, wgate,
                                       ws + WS_MINF, (const int*)(ws + WS_IDXF), out);
}